// Round 10
// baseline (2012.054 us; speedup 1.0000x reference)
//
#include <hip/hip_runtime.h>
#include <cfloat>
#include <cmath>
#include <climits>
#include <cstdint>

// Problem constants
#define N_ROWS   32768
#define D_DIM    512
#define K_CODES  4096

#define EPS_GAP  0.008f     // MFMA-path gap below which we re-check via np-emulation
#define CAND_WIN 0.02f      // fp32-screen window that provably contains the np-argmin
#define FLAG_CAP 12000

typedef short s16x8 __attribute__((ext_vector_type(8)));
typedef float f32x4 __attribute__((ext_vector_type(4)));

// ---------------------------------------------------------------------------
// Flat scratch layout in d_out (float indices).
//   emb_hi  [0, 1048576)   emb_lo [1048576, 2097152)
//   lat_hi  [2097152, 10485760)   lat_lo [10485760, 18874368)
//   e_norm  [18874368, 18878464)  flagcnt [18878464]
//   flaglist[18878465, 18890465)  fidx u16 at [18890496, 18906880)
//   hist    [16777220, 16781316)  (inside lat_lo -> zero AFTER argmin)
//   rowpart [16781316, 16814084)
// Outputs: out_q [0,16777216) loss[16777216] inds[16777217,16809985)
//          emb  [16809985,18907137) perp[18907137]
// ---------------------------------------------------------------------------

__device__ __forceinline__ short f2bf_rne(float x) {
    unsigned u = __float_as_uint(x);
    unsigned r = (u + 0x7fffu + ((u >> 16) & 1u)) >> 16;
    return (short)r;
}
__device__ __forceinline__ float bf2f(short b) {
    return __uint_as_float(((unsigned)(unsigned short)b) << 16);
}

__device__ __forceinline__ void gld16(const short* g, short* l) {
    __builtin_amdgcn_global_load_lds(
        reinterpret_cast<const __attribute__((address_space(1))) unsigned int*>(
            reinterpret_cast<uintptr_t>(g)),
        reinterpret_cast<__attribute__((address_space(3))) unsigned int*>(
            (unsigned int)(reinterpret_cast<uintptr_t>(l))),
        16, 0, 0);
}

// ---------------------------------------------------------------------------
// numpy fp32 pairwise-sum emulation (AVX512/GCC path) -- unchanged, proven.
// ---------------------------------------------------------------------------
__device__ __forceinline__ float np_block128_sq(const float* p) {
    float P[16];
    #pragma unroll
    for (int l = 0; l < 16; ++l) {
        float s0 = __fmul_rn(p[0 * 16 + l], p[0 * 16 + l]);
        float s1 = __fmul_rn(p[1 * 16 + l], p[1 * 16 + l]);
        float s2 = __fmul_rn(p[2 * 16 + l], p[2 * 16 + l]);
        float s3 = __fmul_rn(p[3 * 16 + l], p[3 * 16 + l]);
        float s4 = __fmul_rn(p[4 * 16 + l], p[4 * 16 + l]);
        float s5 = __fmul_rn(p[5 * 16 + l], p[5 * 16 + l]);
        float s6 = __fmul_rn(p[6 * 16 + l], p[6 * 16 + l]);
        float s7 = __fmul_rn(p[7 * 16 + l], p[7 * 16 + l]);
        float a01 = __fadd_rn(s0, s1);
        float a23 = __fadd_rn(s2, s3);
        float a45 = __fadd_rn(s4, s5);
        float a67 = __fadd_rn(s6, s7);
        P[l] = __fadd_rn(__fadd_rn(a01, a23), __fadd_rn(a45, a67));
    }
    float T3[8];
    #pragma unroll
    for (int k = 0; k < 8; ++k) T3[k] = __fadd_rn(P[k], P[k + 8]);
    float T6[4];
    #pragma unroll
    for (int k = 0; k < 4; ++k) T6[k] = __fadd_rn(T3[k], T3[k + 4]);
    return __fadd_rn(__fadd_rn(__fadd_rn(T6[0], T6[1]), T6[2]), T6[3]);
}
__device__ __forceinline__ float np_sum512_sq(const float* p) {
    float B0 = np_block128_sq(p);
    float B1 = np_block128_sq(p + 128);
    float B2 = np_block128_sq(p + 256);
    float B3 = np_block128_sq(p + 384);
    return __fadd_rn(__fadd_rn(B0, B1), __fadd_rn(B2, B3));
}

// ---------------------------------------------------------------------------
// Kernel 0: split fp32 -> bf16 hi/lo for lat and emb.
// ---------------------------------------------------------------------------
__global__ void vq_convert(const float* __restrict__ lat, const float* __restrict__ emb,
                           short* __restrict__ lat_hi, short* __restrict__ lat_lo,
                           short* __restrict__ emb_hi, short* __restrict__ emb_lo) {
    int i = blockIdx.x * 256 + threadIdx.x;
    const float* src; short *dh, *dl; size_t base;
    if (i < 2097152) { src = lat; dh = lat_hi; dl = lat_lo; base = (size_t)i * 8; }
    else             { src = emb; dh = emb_hi; dl = emb_lo; base = (size_t)(i - 2097152) * 8; }
    float4 a = *(const float4*)(src + base);
    float4 b = *(const float4*)(src + base + 4);
    float x[8] = {a.x, a.y, a.z, a.w, b.x, b.y, b.z, b.w};
    s16x8 hv, lv;
    #pragma unroll
    for (int j = 0; j < 8; ++j) {
        short h = f2bf_rne(x[j]);
        hv[j] = h;
        lv[j] = f2bf_rne(x[j] - bf2f(h));
    }
    *(s16x8*)(dh + base) = hv;
    *(s16x8*)(dl + base) = lv;
}

// ---------------------------------------------------------------------------
// Kernel 1: emb row norms (fp32), wave per code.
// ---------------------------------------------------------------------------
__global__ void vq_enorm(const float* __restrict__ emb, float* __restrict__ e_norm) {
    int item = blockIdx.x * 4 + (threadIdx.x >> 6);
    int lane = threadIdx.x & 63;
    const float4* s4 = (const float4*)(emb + (size_t)item * D_DIM);
    float4 a = s4[lane];
    float4 b = s4[64 + lane];
    float s = a.x * a.x + a.y * a.y + a.z * a.z + a.w * a.w
            + b.x * b.x + b.y * b.y + b.z * b.z + b.w * b.w;
    #pragma unroll
    for (int off = 32; off > 0; off >>= 1) s += __shfl_down(s, off);
    if (lane == 0) e_norm[item] = s;
}

// ---------------------------------------------------------------------------
// Kernel 2: MFMA split-bf16 distance GEMM, DOUBLE-BUFFERED prefetch loop
// (T3 minimum 2-phase): stage(next) -> ds_read+MFMA(cur) -> one barrier.
// 256 blocks x 512 thr (8 waves, 2x4). Fused step s = kt*16+dt, 256 steps.
// ---------------------------------------------------------------------------
__device__ __forceinline__ int kswz(int r) { return (r & 3) ^ ((r >> 2) & 3); }

#define BUFS 24576   // shorts per buffer: Ah 4096 | Al 4096 | Bh 8192 | Bl 8192

__global__ __launch_bounds__(512, 2)
void vq_argmin_mfma(const short* __restrict__ Ah_g, const short* __restrict__ Al_g,
                    const short* __restrict__ Bh_g, const short* __restrict__ Bl_g,
                    const float* __restrict__ e_norm,
                    unsigned short* __restrict__ fidx,
                    int* __restrict__ flagcnt, int* __restrict__ flaglist)
{
    __shared__ short smem[2 * BUFS];   // 96KB

    const int tid = threadIdx.x;
    const int l   = tid & 63;
    const int wid = tid >> 6;
    const int wr  = wid >> 2;
    const int wc  = wid & 3;
    const int l15 = l & 15;
    const int lhi = l >> 4;
    const int row0 = blockIdx.x * 128;

    float best[16], sec[16];
    int   bidx[16];
    #pragma unroll
    for (int s = 0; s < 16; ++s) { best[s] = FLT_MAX; sec[s] = FLT_MAX; bidx[s] = 0; }

    int offA[4], offB[4];
    #pragma unroll
    for (int m = 0; m < 4; ++m) {
        int r = wr * 64 + m * 16 + l15;
        offA[m] = r * 32 + (lhi ^ kswz(r)) * 8;
    }
    #pragma unroll
    for (int n = 0; n < 4; ++n) {
        int r = wc * 64 + n * 16 + l15;
        offB[n] = r * 32 + (lhi ^ kswz(r)) * 8;
    }

    // staging address precompute (per thread, step-invariant parts)
    const int ar  = tid >> 2, asl = tid & 3;
    const size_t a_go0 = (size_t)(row0 + ar) * D_DIM + (asl ^ kswz(ar)) * 8;

    // prologue: stage step 0 into buf 0
    {
        gld16(Ah_g + a_go0, smem + tid * 8);
        gld16(Al_g + a_go0, smem + 4096 + tid * 8);
        #pragma unroll
        for (int jj = 0; jj < 2; ++jj) {
            int cc = jj * 512 + tid;
            int rr = cc >> 2, sll = cc & 3;
            size_t go = (size_t)rr * D_DIM + (sll ^ kswz(rr)) * 8;
            gld16(Bh_g + go, smem + 8192 + cc * 8);
            gld16(Bl_g + go, smem + 16384 + cc * 8);
        }
    }
    __syncthreads();

    f32x4 acc[4][4];
    #pragma unroll
    for (int m = 0; m < 4; ++m)
        #pragma unroll
        for (int n = 0; n < 4; ++n) acc[m][n] = (f32x4){0.f, 0.f, 0.f, 0.f};

    for (int s = 0; s < 256; ++s) {
        short* cur = smem + (s & 1) * BUFS;

        // ---- issue next step's staging FIRST (latency hides under compute) --
        if (s < 255) {
            const int s1 = s + 1;
            const int k0 = (s1 & 15) * 32;
            const int cb0 = (s1 >> 4) * 256;
            short* nb = smem + ((s1 & 1)) * BUFS;
            gld16(Ah_g + a_go0 + k0, nb + tid * 8);
            gld16(Al_g + a_go0 + k0, nb + 4096 + tid * 8);
            #pragma unroll
            for (int jj = 0; jj < 2; ++jj) {
                int cc = jj * 512 + tid;
                int rr = cc >> 2, sll = cc & 3;
                size_t go = (size_t)(cb0 + rr) * D_DIM + k0 + (sll ^ kswz(rr)) * 8;
                gld16(Bh_g + go, nb + 8192 + cc * 8);
                gld16(Bl_g + go, nb + 16384 + cc * 8);
            }
        }

        // ---- ds_read fragments of current step ----
        s16x8 ah[4], al[4], bh[4], bl[4];
        #pragma unroll
        for (int m = 0; m < 4; ++m) {
            ah[m] = *(const s16x8*)(cur + offA[m]);
            al[m] = *(const s16x8*)(cur + 4096 + offA[m]);
        }
        #pragma unroll
        for (int n = 0; n < 4; ++n) {
            bh[n] = *(const s16x8*)(cur + 8192 + offB[n]);
            bl[n] = *(const s16x8*)(cur + 16384 + offB[n]);
        }

        // ---- 48 MFMA ----
        #pragma unroll
        for (int m = 0; m < 4; ++m)
            #pragma unroll
            for (int n = 0; n < 4; ++n) {
                acc[m][n] = __builtin_amdgcn_mfma_f32_16x16x32_bf16(ah[m], bh[n], acc[m][n], 0, 0, 0);
                acc[m][n] = __builtin_amdgcn_mfma_f32_16x16x32_bf16(ah[m], bl[n], acc[m][n], 0, 0, 0);
                acc[m][n] = __builtin_amdgcn_mfma_f32_16x16x32_bf16(al[m], bh[n], acc[m][n], 0, 0, 0);
            }

        // ---- per-code-tile epilogue (every 16 steps) ----
        if ((s & 15) == 15) {
            const int cb0 = (s >> 4) * 256;
            #pragma unroll
            for (int n = 0; n < 4; ++n) {
                int c = cb0 + wc * 64 + n * 16 + l15;
                float en = e_norm[c];
                #pragma unroll
                for (int m = 0; m < 4; ++m)
                    #pragma unroll
                    for (int r = 0; r < 4; ++r) {
                        float dv = __fmaf_rn(-2.f, acc[m][n][r], en);
                        int si = m * 4 + r;
                        if (dv < best[si]) { sec[si] = best[si]; best[si] = dv; bidx[si] = c; }
                        else if (dv < sec[si]) sec[si] = dv;
                    }
            }
            #pragma unroll
            for (int m = 0; m < 4; ++m)
                #pragma unroll
                for (int n = 0; n < 4; ++n) acc[m][n] = (f32x4){0.f, 0.f, 0.f, 0.f};
        }

        __syncthreads();   // single barrier: drains staging, protects buffer swap
    }

    // intra-wave reduce across the 16 lanes (l15) sharing each row
    #pragma unroll
    for (int s = 0; s < 16; ++s) {
        float v = best[s], sc = sec[s];
        int ix = bidx[s];
        #pragma unroll
        for (int off = 8; off > 0; off >>= 1) {
            float v2 = __shfl_xor(v, off);
            float s2 = __shfl_xor(sc, off);
            int   i2 = __shfl_xor(ix, off);
            float ns = fminf(fminf(sc, s2), fmaxf(v, v2));
            if (v2 < v || (v2 == v && i2 < ix)) { v = v2; ix = i2; }
            sc = ns;
        }
        best[s] = v; sec[s] = sc; bidx[s] = ix;
    }

    // cross-wave merge via LDS (reuse staging area; last loop barrier passed)
    float* mb = (float*)smem;        // [4][128]
    float* ms = mb + 512;
    int*   mi = (int*)(mb + 1024);
    if (l15 == 0) {
        #pragma unroll
        for (int m = 0; m < 4; ++m)
            #pragma unroll
            for (int r = 0; r < 4; ++r) {
                int s = m * 4 + r;
                int rowblk = wr * 64 + m * 16 + lhi * 4 + r;
                mb[wc * 128 + rowblk] = best[s];
                ms[wc * 128 + rowblk] = sec[s];
                mi[wc * 128 + rowblk] = bidx[s];
            }
    }
    __syncthreads();
    if (tid < 128) {
        float B = FLT_MAX, S = FLT_MAX;
        int I = 0;
        #pragma unroll
        for (int w = 0; w < 4; ++w) {
            float b = mb[w * 128 + tid], s = ms[w * 128 + tid];
            int i = mi[w * 128 + tid];
            if (b < B || (b == B && i < I)) { S = fminf(B, s); B = b; I = i; }
            else S = fminf(S, fminf(b, s));
        }
        int row = row0 + tid;
        fidx[row] = (unsigned short)I;
        if (S - B < EPS_GAP) {
            int p = atomicAdd(flagcnt, 1);
            if (p < FLAG_CAP) flaglist[p] = row;
        }
    }
}

// ---------------------------------------------------------------------------
// Kernel 3: flagged-row resolve, 8 rows share ONE emb sweep per block.
// On-the-fly per-(row,wave) candidate collection with monotone threshold
// (insert when d < runmin+WIN; runmin only decreases => no misses), then
// bit-exact np eval on filtered candidates. Butterfly sums are bitwise
// identical across lanes (fp-add commutativity) => wave-uniform branches.
// ---------------------------------------------------------------------------
#define FIXT  512
#define FCAP  32     // per (row, wave) candidate cap
#define MCAP  64     // merged per-row cap

__global__ __launch_bounds__(FIXT)
void vq_fix8(const float* __restrict__ lat, const float* __restrict__ emb,
             const int* __restrict__ flagcnt, const int* __restrict__ flaglist,
             unsigned short* __restrict__ fidx)
{
    __shared__ float xs[8][D_DIM];          // 16KB
    __shared__ float wmin_s[8][8];          // [row][wave]
    __shared__ int   ccnt[8][8];
    __shared__ int   cidx[8][8][FCAP];      // 8KB
    __shared__ float cdst[8][8][FCAP];      // 8KB
    __shared__ int   mrg_c[8][MCAP];        // 2KB
    __shared__ float mrg_d[8][MCAP];        // 2KB
    __shared__ float ev32[8][MCAP];         // 2KB
    __shared__ int   mnum[8];

    const int t    = threadIdx.x;
    const int wave = t >> 6;
    const int lane = t & 63;
    int cnt = *flagcnt;
    if (cnt > FLAG_CAP) cnt = FLAG_CAP;

    for (int g = blockIdx.x; g * 8 < cnt; g += gridDim.x) {
        int rows[8];
        #pragma unroll
        for (int j = 0; j < 8; ++j) {
            int fi = g * 8 + j; if (fi >= cnt) fi = cnt - 1;   // dup rows benign
            rows[j] = flaglist[fi];
        }
        __syncthreads();   // protect LDS reuse across group iterations
        #pragma unroll
        for (int j = 0; j < 8; ++j) xs[j][t] = lat[(size_t)rows[j] * D_DIM + t];
        if (t < 64) ((int*)ccnt)[t] = 0;
        __syncthreads();

        float x8[8][8];
        #pragma unroll
        for (int j = 0; j < 8; ++j)
            #pragma unroll
            for (int q = 0; q < 8; ++q) x8[j][q] = xs[j][lane * 8 + q];

        float runmin[8];
        #pragma unroll
        for (int j = 0; j < 8; ++j) runmin[j] = FLT_MAX;

        // ---- single fp32 sweep, wave per code, 8 rows amortized ----
        for (int c = wave; c < K_CODES; c += 8) {
            const float4* e4 = (const float4*)(emb + (size_t)c * D_DIM);
            float4 ea = e4[lane * 2];
            float4 eb = e4[lane * 2 + 1];
            float ev[8] = {ea.x, ea.y, ea.z, ea.w, eb.x, eb.y, eb.z, eb.w};
            #pragma unroll
            for (int j = 0; j < 8; ++j) {
                float d0 = x8[j][0] - ev[0], d1 = x8[j][1] - ev[1];
                float d2 = x8[j][2] - ev[2], d3 = x8[j][3] - ev[3];
                float d4 = x8[j][4] - ev[4], d5 = x8[j][5] - ev[5];
                float d6 = x8[j][6] - ev[6], d7 = x8[j][7] - ev[7];
                float sA = __fmaf_rn(d0, d0, __fmaf_rn(d1, d1, __fmaf_rn(d2, d2, d3 * d3)));
                float sB = __fmaf_rn(d4, d4, __fmaf_rn(d5, d5, __fmaf_rn(d6, d6, d7 * d7)));
                float d = sA + sB;
                #pragma unroll
                for (int off = 32; off > 0; off >>= 1) d += __shfl_xor(d, off);
                // wave-uniform candidate insert (stale threshold = conservative)
                if (d < runmin[j] + CAND_WIN) {
                    if (lane == 0) {
                        int p = ccnt[j][wave];
                        ccnt[j][wave] = p + 1;
                        if (p < FCAP) { cidx[j][wave][p] = c; cdst[j][wave][p] = d; }
                    }
                }
                runmin[j] = fminf(runmin[j], d);
            }
        }
        if (lane == 0)
            #pragma unroll
            for (int j = 0; j < 8; ++j) wmin_s[j][wave] = runmin[j];
        __syncthreads();

        // ---- merge per row (wave j owns row j) ----
        {
            int j = wave;
            float gmin = wmin_s[j][0];
            #pragma unroll
            for (int w = 1; w < 8; ++w) gmin = fminf(gmin, wmin_s[j][w]);
            float thr = gmin + CAND_WIN;
            if (lane == 0) {
                int n = 0;
                for (int w = 0; w < 8; ++w) {
                    int nc = ccnt[j][w] < FCAP ? ccnt[j][w] : FCAP;
                    for (int p = 0; p < nc; ++p) {
                        if (cdst[j][w][p] < thr && n < MCAP) {
                            mrg_c[j][n] = cidx[j][w][p];
                            mrg_d[j][n] = cdst[j][w][p];
                            ++n;
                        }
                    }
                }
                mnum[j] = n;
            }
        }
        __syncthreads();

        // ---- bit-exact np eval: wave j evals row j's candidates (lane = ci) --
        {
            int j = wave;
            int nc = mnum[j];
            if (lane < nc) {
                int c = mrg_c[j][lane];
                const float* e = emb + (size_t)c * D_DIM;
                float t1 = np_sum512_sq(xs[j]);
                float t2 = np_sum512_sq(e);
                float dot = 0.f;
                for (int k = 0; k < D_DIM; ++k)
                    dot = __fmaf_rn(xs[j][k], e[k], dot);     // sequential, BLAS order
                ev32[j][lane] = __fsub_rn(__fadd_rn(t1, t2), __fmul_rn(2.f, dot));
            }
        }
        __syncthreads();

        if (lane == 0) {
            int j = wave;
            int nc = mnum[j];
            float bv = ev32[j][0]; int bx = mrg_c[j][0];
            for (int w = 1; w < nc; ++w)
                if (ev32[j][w] < bv || (ev32[j][w] == bv && mrg_c[j][w] < bx)) {
                    bv = ev32[j][w]; bx = mrg_c[j][w];
                }
            fidx[rows[j]] = (unsigned short)bx;
        }
    }
}

// ---------------------------------------------------------------------------
// Kernel 4: gather quantized rows, per-row MSE partial, histogram.
// ---------------------------------------------------------------------------
__global__ void vq_gather(const float* __restrict__ lat, const float* __restrict__ emb,
                          const unsigned short* __restrict__ fidx,
                          float* __restrict__ out_q,
                          float* __restrict__ rowpart, int* __restrict__ hist) {
    int row  = blockIdx.x * 4 + (threadIdx.x >> 6);
    int lane = threadIdx.x & 63;
    int idx  = fidx[row];

    if (lane == 0) atomicAdd(&hist[idx], 1);

    const float4* e4 = (const float4*)(emb + (size_t)idx * D_DIM);
    const float4* x4 = (const float4*)(lat + (size_t)row * D_DIM);
    float4*       q4 = (float4*)(out_q + (size_t)row * D_DIM);

    float s = 0.f;
    #pragma unroll
    for (int i = 0; i < 2; ++i) {
        float4 e = e4[i * 64 + lane];
        float4 x = x4[i * 64 + lane];
        q4[i * 64 + lane] = e;
        float dx = e.x - x.x, dy = e.y - x.y, dz = e.z - x.z, dw = e.w - x.w;
        s += dx * dx + dy * dy + dz * dz + dw * dw;
    }
    #pragma unroll
    for (int off = 32; off > 0; off >>= 1) s += __shfl_down(s, off);
    if (lane == 0) rowpart[row] = s;
}

// ---------------------------------------------------------------------------
// Kernel 5: final reductions (loss, perplexity).
// ---------------------------------------------------------------------------
__global__ void vq_finalize(const float* __restrict__ rowpart, const int* __restrict__ hist,
                            float* __restrict__ out_loss, float* __restrict__ out_perp) {
    __shared__ float sdata[256];
    int t = threadIdx.x;

    float s = 0.f;
    for (int i = t; i < N_ROWS; i += 256) s += rowpart[i];
    sdata[t] = s;
    __syncthreads();
    for (int st = 128; st > 0; st >>= 1) {
        if (t < st) sdata[t] += sdata[t + st];
        __syncthreads();
    }
    if (t == 0) out_loss[0] = 1.05f * (sdata[0] / ((float)N_ROWS * (float)D_DIM));
    __syncthreads();

    float p = 0.f;
    for (int i = t; i < K_CODES; i += 256) {
        float pr = (float)hist[i] / (float)N_ROWS;
        p += pr * logf(pr + 1e-10f);
    }
    sdata[t] = p;
    __syncthreads();
    for (int st = 128; st > 0; st >>= 1) {
        if (t < st) sdata[t] += sdata[t + st];
        __syncthreads();
    }
    if (t == 0) out_perp[0] = expf(-sdata[0]);
}

// ---------------------------------------------------------------------------
// Kernel 6: fidx u16 -> out_inds float.
// ---------------------------------------------------------------------------
__global__ void vq_inds(const unsigned short* __restrict__ fidx, float* __restrict__ out_inds) {
    int i = blockIdx.x * 1024 + threadIdx.x;
    out_inds[i] = (float)fidx[i];
}

// ---------------------------------------------------------------------------
extern "C" void kernel_launch(void* const* d_in, const int* in_sizes, int n_in,
                              void* d_out, int out_size, void* d_ws, size_t ws_size,
                              hipStream_t stream) {
    const float* lat = (const float*)d_in[0];
    const float* emb = (const float*)d_in[1];
    float* ob = (float*)d_out;

    short* emb_hi = (short*)(ob + 0);
    short* emb_lo = (short*)(ob + 1048576);
    short* lat_hi = (short*)(ob + 2097152);
    short* lat_lo = (short*)(ob + 10485760);
    float* e_norm = ob + 18874368;
    int*   flagcnt  = (int*)(ob + 18878464);
    int*   flaglist = (int*)(ob + 18878465);
    unsigned short* fidx = (unsigned short*)(ob + 18890496);
    int*   hist    = (int*)(ob + 16777220);
    float* rowpart = ob + 16781316;

    float* out_q    = ob;
    float* out_loss = ob + 16777216;
    float* out_inds = ob + 16777217;
    float* out_emb  = ob + 16809985;
    float* out_perp = ob + 18907137;

    // flagcnt lives in the clean tail (never touched by vq_convert) -> zero now.
    hipMemsetAsync(flagcnt, 0, sizeof(int), stream);

    vq_convert<<<dim3(9216), dim3(256), 0, stream>>>(lat, emb, lat_hi, lat_lo, emb_hi, emb_lo);
    vq_enorm<<<dim3(1024), dim3(256), 0, stream>>>(emb, e_norm);

    vq_argmin_mfma<<<dim3(256), dim3(512), 0, stream>>>(lat_hi, lat_lo, emb_hi, emb_lo,
                                                        e_norm, fidx, flagcnt, flaglist);

    // hist overlaps lat_lo -> zero it only AFTER the argmin consumed lat_lo.
    hipMemsetAsync(hist, 0, K_CODES * sizeof(int), stream);

    vq_fix8<<<dim3(128), dim3(FIXT), 0, stream>>>(lat, emb, flagcnt, flaglist, fidx);

    vq_gather<<<dim3(N_ROWS / 4), dim3(256), 0, stream>>>(lat, emb, fidx, out_q, rowpart, hist);

    vq_finalize<<<dim3(1), dim3(256), 0, stream>>>(rowpart, hist, out_loss, out_perp);

    vq_inds<<<dim3(32), dim3(1024), 0, stream>>>(fidx, out_inds);

    hipMemcpyAsync(out_emb, emb, (size_t)K_CODES * D_DIM * sizeof(float),
                   hipMemcpyDeviceToDevice, stream);
}

// Round 11
// 845.855 us; speedup vs baseline: 2.3787x; 2.3787x over previous
//
#include <hip/hip_runtime.h>
#include <cfloat>
#include <cmath>
#include <climits>
#include <cstdint>

// Problem constants
#define N_ROWS   32768
#define D_DIM    512
#define K_CODES  4096

#define EPS_GAP  0.008f     // MFMA-path gap below which we re-check via np-emulation
#define CAND_WIN 0.02f      // fp32-screen window that provably contains the np-argmin
#define FLAG_CAP 12000

typedef short s16x8 __attribute__((ext_vector_type(8)));
typedef float f32x4 __attribute__((ext_vector_type(4)));

// ---------------------------------------------------------------------------
// Flat scratch layout in d_out (float indices).
//   emb_hi  [0, 1048576)   emb_lo [1048576, 2097152)
//   lat_hi  [2097152, 10485760)   lat_lo [10485760, 18874368)
//   e_norm  [18874368, 18878464)  flagcnt [18878464]
//   flaglist[18878465, 18890465)  fidx u16 at [18890496, 18906880)
//   hist    [16777220, 16781316)  (inside lat_lo -> zero AFTER argmin)
//   rowpart [16781316, 16814084)
// Outputs: out_q [0,16777216) loss[16777216] inds[16777217,16809985)
//          emb  [16809985,18907137) perp[18907137]
// ---------------------------------------------------------------------------

__device__ __forceinline__ short f2bf_rne(float x) {
    unsigned u = __float_as_uint(x);
    unsigned r = (u + 0x7fffu + ((u >> 16) & 1u)) >> 16;
    return (short)r;
}
__device__ __forceinline__ float bf2f(short b) {
    return __uint_as_float(((unsigned)(unsigned short)b) << 16);
}

__device__ __forceinline__ void gld16(const short* g, short* l) {
    __builtin_amdgcn_global_load_lds(
        reinterpret_cast<const __attribute__((address_space(1))) unsigned int*>(
            reinterpret_cast<uintptr_t>(g)),
        reinterpret_cast<__attribute__((address_space(3))) unsigned int*>(
            (unsigned int)(reinterpret_cast<uintptr_t>(l))),
        16, 0, 0);
}

// ---------------------------------------------------------------------------
// numpy fp32 pairwise-sum emulation (AVX512/GCC path) -- unchanged, proven.
// ---------------------------------------------------------------------------
__device__ __forceinline__ float np_block128_sq(const float* p) {
    float P[16];
    #pragma unroll
    for (int l = 0; l < 16; ++l) {
        float s0 = __fmul_rn(p[0 * 16 + l], p[0 * 16 + l]);
        float s1 = __fmul_rn(p[1 * 16 + l], p[1 * 16 + l]);
        float s2 = __fmul_rn(p[2 * 16 + l], p[2 * 16 + l]);
        float s3 = __fmul_rn(p[3 * 16 + l], p[3 * 16 + l]);
        float s4 = __fmul_rn(p[4 * 16 + l], p[4 * 16 + l]);
        float s5 = __fmul_rn(p[5 * 16 + l], p[5 * 16 + l]);
        float s6 = __fmul_rn(p[6 * 16 + l], p[6 * 16 + l]);
        float s7 = __fmul_rn(p[7 * 16 + l], p[7 * 16 + l]);
        float a01 = __fadd_rn(s0, s1);
        float a23 = __fadd_rn(s2, s3);
        float a45 = __fadd_rn(s4, s5);
        float a67 = __fadd_rn(s6, s7);
        P[l] = __fadd_rn(__fadd_rn(a01, a23), __fadd_rn(a45, a67));
    }
    float T3[8];
    #pragma unroll
    for (int k = 0; k < 8; ++k) T3[k] = __fadd_rn(P[k], P[k + 8]);
    float T6[4];
    #pragma unroll
    for (int k = 0; k < 4; ++k) T6[k] = __fadd_rn(T3[k], T3[k + 4]);
    return __fadd_rn(__fadd_rn(__fadd_rn(T6[0], T6[1]), T6[2]), T6[3]);
}
__device__ __forceinline__ float np_sum512_sq(const float* p) {
    float B0 = np_block128_sq(p);
    float B1 = np_block128_sq(p + 128);
    float B2 = np_block128_sq(p + 256);
    float B3 = np_block128_sq(p + 384);
    return __fadd_rn(__fadd_rn(B0, B1), __fadd_rn(B2, B3));
}

// ---------------------------------------------------------------------------
// Kernel 0: split fp32 -> bf16 hi/lo for lat and emb.
// ---------------------------------------------------------------------------
__global__ void vq_convert(const float* __restrict__ lat, const float* __restrict__ emb,
                           short* __restrict__ lat_hi, short* __restrict__ lat_lo,
                           short* __restrict__ emb_hi, short* __restrict__ emb_lo) {
    int i = blockIdx.x * 256 + threadIdx.x;
    const float* src; short *dh, *dl; size_t base;
    if (i < 2097152) { src = lat; dh = lat_hi; dl = lat_lo; base = (size_t)i * 8; }
    else             { src = emb; dh = emb_hi; dl = emb_lo; base = (size_t)(i - 2097152) * 8; }
    float4 a = *(const float4*)(src + base);
    float4 b = *(const float4*)(src + base + 4);
    float x[8] = {a.x, a.y, a.z, a.w, b.x, b.y, b.z, b.w};
    s16x8 hv, lv;
    #pragma unroll
    for (int j = 0; j < 8; ++j) {
        short h = f2bf_rne(x[j]);
        hv[j] = h;
        lv[j] = f2bf_rne(x[j] - bf2f(h));
    }
    *(s16x8*)(dh + base) = hv;
    *(s16x8*)(dl + base) = lv;
}

// ---------------------------------------------------------------------------
// Kernel 1: emb row norms (fp32), wave per code.
// ---------------------------------------------------------------------------
__global__ void vq_enorm(const float* __restrict__ emb, float* __restrict__ e_norm) {
    int item = blockIdx.x * 4 + (threadIdx.x >> 6);
    int lane = threadIdx.x & 63;
    const float4* s4 = (const float4*)(emb + (size_t)item * D_DIM);
    float4 a = s4[lane];
    float4 b = s4[64 + lane];
    float s = a.x * a.x + a.y * a.y + a.z * a.z + a.w * a.w
            + b.x * b.x + b.y * b.y + b.z * b.z + b.w * b.w;
    #pragma unroll
    for (int off = 32; off > 0; off >>= 1) s += __shfl_down(s, off);
    if (lane == 0) e_norm[item] = s;
}

// ---------------------------------------------------------------------------
// Kernel 2: MFMA split-bf16 distance GEMM, DOUBLE-BUFFERED prefetch loop.
// (byte-identical to the round-10 version that passed)
// ---------------------------------------------------------------------------
__device__ __forceinline__ int kswz(int r) { return (r & 3) ^ ((r >> 2) & 3); }

#define BUFS 24576   // shorts per buffer: Ah 4096 | Al 4096 | Bh 8192 | Bl 8192

__global__ __launch_bounds__(512, 2)
void vq_argmin_mfma(const short* __restrict__ Ah_g, const short* __restrict__ Al_g,
                    const short* __restrict__ Bh_g, const short* __restrict__ Bl_g,
                    const float* __restrict__ e_norm,
                    unsigned short* __restrict__ fidx,
                    int* __restrict__ flagcnt, int* __restrict__ flaglist)
{
    __shared__ short smem[2 * BUFS];   // 96KB

    const int tid = threadIdx.x;
    const int l   = tid & 63;
    const int wid = tid >> 6;
    const int wr  = wid >> 2;
    const int wc  = wid & 3;
    const int l15 = l & 15;
    const int lhi = l >> 4;
    const int row0 = blockIdx.x * 128;

    float best[16], sec[16];
    int   bidx[16];
    #pragma unroll
    for (int s = 0; s < 16; ++s) { best[s] = FLT_MAX; sec[s] = FLT_MAX; bidx[s] = 0; }

    int offA[4], offB[4];
    #pragma unroll
    for (int m = 0; m < 4; ++m) {
        int r = wr * 64 + m * 16 + l15;
        offA[m] = r * 32 + (lhi ^ kswz(r)) * 8;
    }
    #pragma unroll
    for (int n = 0; n < 4; ++n) {
        int r = wc * 64 + n * 16 + l15;
        offB[n] = r * 32 + (lhi ^ kswz(r)) * 8;
    }

    const int ar  = tid >> 2, asl = tid & 3;
    const size_t a_go0 = (size_t)(row0 + ar) * D_DIM + (asl ^ kswz(ar)) * 8;

    {
        gld16(Ah_g + a_go0, smem + tid * 8);
        gld16(Al_g + a_go0, smem + 4096 + tid * 8);
        #pragma unroll
        for (int jj = 0; jj < 2; ++jj) {
            int cc = jj * 512 + tid;
            int rr = cc >> 2, sll = cc & 3;
            size_t go = (size_t)rr * D_DIM + (sll ^ kswz(rr)) * 8;
            gld16(Bh_g + go, smem + 8192 + cc * 8);
            gld16(Bl_g + go, smem + 16384 + cc * 8);
        }
    }
    __syncthreads();

    f32x4 acc[4][4];
    #pragma unroll
    for (int m = 0; m < 4; ++m)
        #pragma unroll
        for (int n = 0; n < 4; ++n) acc[m][n] = (f32x4){0.f, 0.f, 0.f, 0.f};

    for (int s = 0; s < 256; ++s) {
        short* cur = smem + (s & 1) * BUFS;

        if (s < 255) {
            const int s1 = s + 1;
            const int k0 = (s1 & 15) * 32;
            const int cb0 = (s1 >> 4) * 256;
            short* nb = smem + ((s1 & 1)) * BUFS;
            gld16(Ah_g + a_go0 + k0, nb + tid * 8);
            gld16(Al_g + a_go0 + k0, nb + 4096 + tid * 8);
            #pragma unroll
            for (int jj = 0; jj < 2; ++jj) {
                int cc = jj * 512 + tid;
                int rr = cc >> 2, sll = cc & 3;
                size_t go = (size_t)(cb0 + rr) * D_DIM + k0 + (sll ^ kswz(rr)) * 8;
                gld16(Bh_g + go, nb + 8192 + cc * 8);
                gld16(Bl_g + go, nb + 16384 + cc * 8);
            }
        }

        s16x8 ah[4], al[4], bh[4], bl[4];
        #pragma unroll
        for (int m = 0; m < 4; ++m) {
            ah[m] = *(const s16x8*)(cur + offA[m]);
            al[m] = *(const s16x8*)(cur + 4096 + offA[m]);
        }
        #pragma unroll
        for (int n = 0; n < 4; ++n) {
            bh[n] = *(const s16x8*)(cur + 8192 + offB[n]);
            bl[n] = *(const s16x8*)(cur + 16384 + offB[n]);
        }

        #pragma unroll
        for (int m = 0; m < 4; ++m)
            #pragma unroll
            for (int n = 0; n < 4; ++n) {
                acc[m][n] = __builtin_amdgcn_mfma_f32_16x16x32_bf16(ah[m], bh[n], acc[m][n], 0, 0, 0);
                acc[m][n] = __builtin_amdgcn_mfma_f32_16x16x32_bf16(ah[m], bl[n], acc[m][n], 0, 0, 0);
                acc[m][n] = __builtin_amdgcn_mfma_f32_16x16x32_bf16(al[m], bh[n], acc[m][n], 0, 0, 0);
            }

        if ((s & 15) == 15) {
            const int cb0 = (s >> 4) * 256;
            #pragma unroll
            for (int n = 0; n < 4; ++n) {
                int c = cb0 + wc * 64 + n * 16 + l15;
                float en = e_norm[c];
                #pragma unroll
                for (int m = 0; m < 4; ++m)
                    #pragma unroll
                    for (int r = 0; r < 4; ++r) {
                        float dv = __fmaf_rn(-2.f, acc[m][n][r], en);
                        int si = m * 4 + r;
                        if (dv < best[si]) { sec[si] = best[si]; best[si] = dv; bidx[si] = c; }
                        else if (dv < sec[si]) sec[si] = dv;
                    }
            }
            #pragma unroll
            for (int m = 0; m < 4; ++m)
                #pragma unroll
                for (int n = 0; n < 4; ++n) acc[m][n] = (f32x4){0.f, 0.f, 0.f, 0.f};
        }

        __syncthreads();
    }

    #pragma unroll
    for (int s = 0; s < 16; ++s) {
        float v = best[s], sc = sec[s];
        int ix = bidx[s];
        #pragma unroll
        for (int off = 8; off > 0; off >>= 1) {
            float v2 = __shfl_xor(v, off);
            float s2 = __shfl_xor(sc, off);
            int   i2 = __shfl_xor(ix, off);
            float ns = fminf(fminf(sc, s2), fmaxf(v, v2));
            if (v2 < v || (v2 == v && i2 < ix)) { v = v2; ix = i2; }
            sc = ns;
        }
        best[s] = v; sec[s] = sc; bidx[s] = ix;
    }

    float* mb = (float*)smem;        // [4][128]
    float* ms = mb + 512;
    int*   mi = (int*)(mb + 1024);
    if (l15 == 0) {
        #pragma unroll
        for (int m = 0; m < 4; ++m)
            #pragma unroll
            for (int r = 0; r < 4; ++r) {
                int s = m * 4 + r;
                int rowblk = wr * 64 + m * 16 + lhi * 4 + r;
                mb[wc * 128 + rowblk] = best[s];
                ms[wc * 128 + rowblk] = sec[s];
                mi[wc * 128 + rowblk] = bidx[s];
            }
    }
    __syncthreads();
    if (tid < 128) {
        float B = FLT_MAX, S = FLT_MAX;
        int I = 0;
        #pragma unroll
        for (int w = 0; w < 4; ++w) {
            float b = mb[w * 128 + tid], s = ms[w * 128 + tid];
            int i = mi[w * 128 + tid];
            if (b < B || (b == B && i < I)) { S = fminf(B, s); B = b; I = i; }
            else S = fminf(S, fminf(b, s));
        }
        int row = row0 + tid;
        fidx[row] = (unsigned short)I;
        if (S - B < EPS_GAP) {
            int p = atomicAdd(flagcnt, 1);
            if (p < FLAG_CAP) flaglist[p] = row;
        }
    }
}

// ---------------------------------------------------------------------------
// Kernel 3: flagged-row resolve — ONE row per block (restores round-9
// parallelism: ~290 concurrent blocks), 1024 threads = 16 waves (halves each
// wave's serial code count), sweep unrolled x2 (two independent
// load+butterfly chains in flight). Then bit-exact np eval on candidates.
// ---------------------------------------------------------------------------
#define FIXT 1024
#define NWAV 16
#define MAXC 128

__global__ __launch_bounds__(FIXT)
void vq_fixrow(const float* __restrict__ lat, const float* __restrict__ emb,
               const int* __restrict__ flagcnt, const int* __restrict__ flaglist,
               unsigned short* __restrict__ fidx)
{
    __shared__ float xs[D_DIM];
    __shared__ float dall[K_CODES];     // 16 KB
    __shared__ float wmin_s[NWAV];
    __shared__ int   ccnt;
    __shared__ int   cands[MAXC];
    __shared__ float cd32[MAXC];

    const int t    = threadIdx.x;
    const int wave = t >> 6;
    const int lane = t & 63;
    int cnt = *flagcnt;
    if (cnt > FLAG_CAP) cnt = FLAG_CAP;

    for (int f = blockIdx.x; f < cnt; f += gridDim.x) {
        const int row = flaglist[f];
        __syncthreads();   // protect LDS reuse across row iterations
        if (t < D_DIM) xs[t] = lat[(size_t)row * D_DIM + t];
        if (t == 0) ccnt = 0;
        __syncthreads();

        float x8[8];
        #pragma unroll
        for (int q = 0; q < 8; ++q) x8[q] = xs[lane * 8 + q];

        // ---- fp32 screening sweep: wave-per-code, 2 codes in flight ----
        float lmin = FLT_MAX;
        for (int c = wave; c < K_CODES; c += 2 * NWAV) {
            const int c2 = c + NWAV;
            const float4* e4a = (const float4*)(emb + (size_t)c  * D_DIM);
            const float4* e4b = (const float4*)(emb + (size_t)c2 * D_DIM);
            float4 ea0 = e4a[lane * 2], ea1 = e4a[lane * 2 + 1];
            float4 eb0 = e4b[lane * 2], eb1 = e4b[lane * 2 + 1];

            float p0 = x8[0] - ea0.x, p1 = x8[1] - ea0.y;
            float p2 = x8[2] - ea0.z, p3 = x8[3] - ea0.w;
            float p4 = x8[4] - ea1.x, p5 = x8[5] - ea1.y;
            float p6 = x8[6] - ea1.z, p7 = x8[7] - ea1.w;
            float sA = __fmaf_rn(p0, p0, __fmaf_rn(p1, p1, __fmaf_rn(p2, p2, p3 * p3)));
            float sB = __fmaf_rn(p4, p4, __fmaf_rn(p5, p5, __fmaf_rn(p6, p6, p7 * p7)));
            float u = sA + sB;

            float q0 = x8[0] - eb0.x, q1 = x8[1] - eb0.y;
            float q2 = x8[2] - eb0.z, q3 = x8[3] - eb0.w;
            float q4 = x8[4] - eb1.x, q5 = x8[5] - eb1.y;
            float q6 = x8[6] - eb1.z, q7 = x8[7] - eb1.w;
            float tA = __fmaf_rn(q0, q0, __fmaf_rn(q1, q1, __fmaf_rn(q2, q2, q3 * q3)));
            float tB = __fmaf_rn(q4, q4, __fmaf_rn(q5, q5, __fmaf_rn(q6, q6, q7 * q7)));
            float v = tA + tB;

            #pragma unroll
            for (int off = 32; off > 0; off >>= 1) {
                u += __shfl_xor(u, off);
                v += __shfl_xor(v, off);
            }
            if (lane == 0) { dall[c] = u; dall[c2] = v; }
            lmin = fminf(lmin, fminf(u, v));
        }
        if (lane == 0) wmin_s[wave] = lmin;
        __syncthreads();

        float gmin = wmin_s[0];
        #pragma unroll
        for (int w = 1; w < NWAV; ++w) gmin = fminf(gmin, wmin_s[w]);
        const float thr = gmin + CAND_WIN;

        for (int c = t; c < K_CODES; c += FIXT) {
            if (dall[c] < thr) {
                int p = atomicAdd(&ccnt, 1);
                if (p < MAXC) cands[p] = c;
            }
        }
        __syncthreads();

        // ---- bit-exact np eval on candidates ----
        int nc = ccnt < MAXC ? ccnt : MAXC;
        if (t < nc) {
            int c = cands[t];
            const float* e = emb + (size_t)c * D_DIM;
            float t1 = np_sum512_sq(xs);
            float t2 = np_sum512_sq(e);
            float dot = 0.f;
            for (int k = 0; k < D_DIM; ++k)
                dot = __fmaf_rn(xs[k], e[k], dot);     // sequential, BLAS order
            cd32[t] = __fsub_rn(__fadd_rn(t1, t2), __fmul_rn(2.f, dot));
        }
        __syncthreads();

        if (t == 0) {
            float bv = cd32[0]; int bx = cands[0];
            for (int w = 1; w < nc; ++w)
                if (cd32[w] < bv || (cd32[w] == bv && cands[w] < bx)) {
                    bv = cd32[w]; bx = cands[w];
                }
            fidx[row] = (unsigned short)bx;
        }
    }
}

// ---------------------------------------------------------------------------
// Kernel 4: gather quantized rows, per-row MSE partial, histogram.
// ---------------------------------------------------------------------------
__global__ void vq_gather(const float* __restrict__ lat, const float* __restrict__ emb,
                          const unsigned short* __restrict__ fidx,
                          float* __restrict__ out_q,
                          float* __restrict__ rowpart, int* __restrict__ hist) {
    int row  = blockIdx.x * 4 + (threadIdx.x >> 6);
    int lane = threadIdx.x & 63;
    int idx  = fidx[row];

    if (lane == 0) atomicAdd(&hist[idx], 1);

    const float4* e4 = (const float4*)(emb + (size_t)idx * D_DIM);
    const float4* x4 = (const float4*)(lat + (size_t)row * D_DIM);
    float4*       q4 = (float4*)(out_q + (size_t)row * D_DIM);

    float s = 0.f;
    #pragma unroll
    for (int i = 0; i < 2; ++i) {
        float4 e = e4[i * 64 + lane];
        float4 x = x4[i * 64 + lane];
        q4[i * 64 + lane] = e;
        float dx = e.x - x.x, dy = e.y - x.y, dz = e.z - x.z, dw = e.w - x.w;
        s += dx * dx + dy * dy + dz * dz + dw * dw;
    }
    #pragma unroll
    for (int off = 32; off > 0; off >>= 1) s += __shfl_down(s, off);
    if (lane == 0) rowpart[row] = s;
}

// ---------------------------------------------------------------------------
// Kernel 5: final reductions (loss, perplexity).
// ---------------------------------------------------------------------------
__global__ void vq_finalize(const float* __restrict__ rowpart, const int* __restrict__ hist,
                            float* __restrict__ out_loss, float* __restrict__ out_perp) {
    __shared__ float sdata[256];
    int t = threadIdx.x;

    float s = 0.f;
    for (int i = t; i < N_ROWS; i += 256) s += rowpart[i];
    sdata[t] = s;
    __syncthreads();
    for (int st = 128; st > 0; st >>= 1) {
        if (t < st) sdata[t] += sdata[t + st];
        __syncthreads();
    }
    if (t == 0) out_loss[0] = 1.05f * (sdata[0] / ((float)N_ROWS * (float)D_DIM));
    __syncthreads();

    float p = 0.f;
    for (int i = t; i < K_CODES; i += 256) {
        float pr = (float)hist[i] / (float)N_ROWS;
        p += pr * logf(pr + 1e-10f);
    }
    sdata[t] = p;
    __syncthreads();
    for (int st = 128; st > 0; st >>= 1) {
        if (t < st) sdata[t] += sdata[t + st];
        __syncthreads();
    }
    if (t == 0) out_perp[0] = expf(-sdata[0]);
}

// ---------------------------------------------------------------------------
// Kernel 6: fidx u16 -> out_inds float.
// ---------------------------------------------------------------------------
__global__ void vq_inds(const unsigned short* __restrict__ fidx, float* __restrict__ out_inds) {
    int i = blockIdx.x * 1024 + threadIdx.x;
    out_inds[i] = (float)fidx[i];
}

// ---------------------------------------------------------------------------
extern "C" void kernel_launch(void* const* d_in, const int* in_sizes, int n_in,
                              void* d_out, int out_size, void* d_ws, size_t ws_size,
                              hipStream_t stream) {
    const float* lat = (const float*)d_in[0];
    const float* emb = (const float*)d_in[1];
    float* ob = (float*)d_out;

    short* emb_hi = (short*)(ob + 0);
    short* emb_lo = (short*)(ob + 1048576);
    short* lat_hi = (short*)(ob + 2097152);
    short* lat_lo = (short*)(ob + 10485760);
    float* e_norm = ob + 18874368;
    int*   flagcnt  = (int*)(ob + 18878464);
    int*   flaglist = (int*)(ob + 18878465);
    unsigned short* fidx = (unsigned short*)(ob + 18890496);
    int*   hist    = (int*)(ob + 16777220);
    float* rowpart = ob + 16781316;

    float* out_q    = ob;
    float* out_loss = ob + 16777216;
    float* out_inds = ob + 16777217;
    float* out_emb  = ob + 16809985;
    float* out_perp = ob + 18907137;

    // flagcnt lives in the clean tail (never touched by vq_convert) -> zero now.
    hipMemsetAsync(flagcnt, 0, sizeof(int), stream);

    vq_convert<<<dim3(9216), dim3(256), 0, stream>>>(lat, emb, lat_hi, lat_lo, emb_hi, emb_lo);
    vq_enorm<<<dim3(1024), dim3(256), 0, stream>>>(emb, e_norm);

    vq_argmin_mfma<<<dim3(256), dim3(512), 0, stream>>>(lat_hi, lat_lo, emb_hi, emb_lo,
                                                        e_norm, fidx, flagcnt, flaglist);

    // hist overlaps lat_lo -> zero it only AFTER the argmin consumed lat_lo.
    hipMemsetAsync(hist, 0, K_CODES * sizeof(int), stream);

    vq_fixrow<<<dim3(512), dim3(FIXT), 0, stream>>>(lat, emb, flagcnt, flaglist, fidx);

    vq_gather<<<dim3(N_ROWS / 4), dim3(256), 0, stream>>>(lat, emb, fidx, out_q, rowpart, hist);

    vq_finalize<<<dim3(1), dim3(256), 0, stream>>>(rowpart, hist, out_loss, out_perp);

    vq_inds<<<dim3(32), dim3(1024), 0, stream>>>(fidx, out_inds);

    hipMemcpyAsync(out_emb, emb, (size_t)K_CODES * D_DIM * sizeof(float),
                   hipMemcpyDeviceToDevice, stream);
}

// Round 12
// 745.770 us; speedup vs baseline: 2.6980x; 1.1342x over previous
//
#include <hip/hip_runtime.h>
#include <cfloat>
#include <cmath>
#include <climits>
#include <cstdint>

// Problem constants
#define N_ROWS   32768
#define D_DIM    512
#define K_CODES  4096

#define EPS_GAP  0.008f     // MFMA-path gap below which we re-check via np-emulation
#define CAND_WIN 0.02f      // fp32-screen window that provably contains the np-argmin
#define FLAG_CAP 12000

typedef short s16x8 __attribute__((ext_vector_type(8)));
typedef float f32x4 __attribute__((ext_vector_type(4)));

// ---------------------------------------------------------------------------
// Flat scratch layout in d_out (float indices).
//   emb_hi  [0, 1048576)   emb_lo [1048576, 2097152)
//   lat_hi  [2097152, 10485760)   lat_lo [10485760, 18874368)
//   e_norm  [18874368, 18878464)  flagcnt [18878464]
//   flaglist[18878465, 18890465)  fidx u16 at [18890496, 18906880)
//   hist    [16777220, 16781316)  (inside lat_lo -> zero AFTER argmin)
//   rowpart [16781316, 16814084)
// Outputs: out_q [0,16777216) loss[16777216] inds[16777217,16809985)
//          emb  [16809985,18907137) perp[18907137]
// ---------------------------------------------------------------------------

__device__ __forceinline__ short f2bf_rne(float x) {
    unsigned u = __float_as_uint(x);
    unsigned r = (u + 0x7fffu + ((u >> 16) & 1u)) >> 16;
    return (short)r;
}
__device__ __forceinline__ float bf2f(short b) {
    return __uint_as_float(((unsigned)(unsigned short)b) << 16);
}

__device__ __forceinline__ void gld16(const short* g, short* l) {
    __builtin_amdgcn_global_load_lds(
        reinterpret_cast<const __attribute__((address_space(1))) unsigned int*>(
            reinterpret_cast<uintptr_t>(g)),
        reinterpret_cast<__attribute__((address_space(3))) unsigned int*>(
            (unsigned int)(reinterpret_cast<uintptr_t>(l))),
        16, 0, 0);
}

// ---------------------------------------------------------------------------
// numpy fp32 pairwise-sum emulation (AVX512/GCC path) -- unchanged, proven.
// ---------------------------------------------------------------------------
__device__ __forceinline__ float np_block128_sq(const float* p) {
    float P[16];
    #pragma unroll
    for (int l = 0; l < 16; ++l) {
        float s0 = __fmul_rn(p[0 * 16 + l], p[0 * 16 + l]);
        float s1 = __fmul_rn(p[1 * 16 + l], p[1 * 16 + l]);
        float s2 = __fmul_rn(p[2 * 16 + l], p[2 * 16 + l]);
        float s3 = __fmul_rn(p[3 * 16 + l], p[3 * 16 + l]);
        float s4 = __fmul_rn(p[4 * 16 + l], p[4 * 16 + l]);
        float s5 = __fmul_rn(p[5 * 16 + l], p[5 * 16 + l]);
        float s6 = __fmul_rn(p[6 * 16 + l], p[6 * 16 + l]);
        float s7 = __fmul_rn(p[7 * 16 + l], p[7 * 16 + l]);
        float a01 = __fadd_rn(s0, s1);
        float a23 = __fadd_rn(s2, s3);
        float a45 = __fadd_rn(s4, s5);
        float a67 = __fadd_rn(s6, s7);
        P[l] = __fadd_rn(__fadd_rn(a01, a23), __fadd_rn(a45, a67));
    }
    float T3[8];
    #pragma unroll
    for (int k = 0; k < 8; ++k) T3[k] = __fadd_rn(P[k], P[k + 8]);
    float T6[4];
    #pragma unroll
    for (int k = 0; k < 4; ++k) T6[k] = __fadd_rn(T3[k], T3[k + 4]);
    return __fadd_rn(__fadd_rn(__fadd_rn(T6[0], T6[1]), T6[2]), T6[3]);
}
__device__ __forceinline__ float np_sum512_sq(const float* p) {
    float B0 = np_block128_sq(p);
    float B1 = np_block128_sq(p + 128);
    float B2 = np_block128_sq(p + 256);
    float B3 = np_block128_sq(p + 384);
    return __fadd_rn(__fadd_rn(B0, B1), __fadd_rn(B2, B3));
}

// ---------------------------------------------------------------------------
// Kernel 0: split fp32 -> bf16 hi/lo for lat and emb.
// ---------------------------------------------------------------------------
__global__ void vq_convert(const float* __restrict__ lat, const float* __restrict__ emb,
                           short* __restrict__ lat_hi, short* __restrict__ lat_lo,
                           short* __restrict__ emb_hi, short* __restrict__ emb_lo) {
    int i = blockIdx.x * 256 + threadIdx.x;
    const float* src; short *dh, *dl; size_t base;
    if (i < 2097152) { src = lat; dh = lat_hi; dl = lat_lo; base = (size_t)i * 8; }
    else             { src = emb; dh = emb_hi; dl = emb_lo; base = (size_t)(i - 2097152) * 8; }
    float4 a = *(const float4*)(src + base);
    float4 b = *(const float4*)(src + base + 4);
    float x[8] = {a.x, a.y, a.z, a.w, b.x, b.y, b.z, b.w};
    s16x8 hv, lv;
    #pragma unroll
    for (int j = 0; j < 8; ++j) {
        short h = f2bf_rne(x[j]);
        hv[j] = h;
        lv[j] = f2bf_rne(x[j] - bf2f(h));
    }
    *(s16x8*)(dh + base) = hv;
    *(s16x8*)(dl + base) = lv;
}

// ---------------------------------------------------------------------------
// Kernel 1: emb row norms (fp32), wave per code.
// ---------------------------------------------------------------------------
__global__ void vq_enorm(const float* __restrict__ emb, float* __restrict__ e_norm) {
    int item = blockIdx.x * 4 + (threadIdx.x >> 6);
    int lane = threadIdx.x & 63;
    const float4* s4 = (const float4*)(emb + (size_t)item * D_DIM);
    float4 a = s4[lane];
    float4 b = s4[64 + lane];
    float s = a.x * a.x + a.y * a.y + a.z * a.z + a.w * a.w
            + b.x * b.x + b.y * b.y + b.z * b.z + b.w * b.w;
    #pragma unroll
    for (int off = 32; off > 0; off >>= 1) s += __shfl_down(s, off);
    if (lane == 0) e_norm[item] = s;
}

// ---------------------------------------------------------------------------
// Kernel 2: MFMA split-bf16 distance GEMM, double-buffered, 16 WAVES/block
// (4x4 wave grid; each wave 32 rows x 64 cols, 24 MFMA/step). Same numerics
// and reduce semantics as the 8-wave version; only thread mapping changed.
// ---------------------------------------------------------------------------
__device__ __forceinline__ int kswz(int r) { return (r & 3) ^ ((r >> 2) & 3); }

#define BUFS 24576   // shorts per buffer: Ah 4096 | Al 4096 | Bh 8192 | Bl 8192

__global__ __launch_bounds__(1024, 4)
void vq_argmin_mfma(const short* __restrict__ Ah_g, const short* __restrict__ Al_g,
                    const short* __restrict__ Bh_g, const short* __restrict__ Bl_g,
                    const float* __restrict__ e_norm,
                    unsigned short* __restrict__ fidx,
                    int* __restrict__ flagcnt, int* __restrict__ flaglist)
{
    __shared__ short smem[2 * BUFS];   // 96KB

    const int tid = threadIdx.x;
    const int l   = tid & 63;
    const int wid = tid >> 6;      // 0..15
    const int wr  = wid >> 2;      // 0..3 -> rows wr*32..+31
    const int wc  = wid & 3;       // 0..3 -> cols wc*64..+63
    const int l15 = l & 15;
    const int lhi = l >> 4;
    const int row0 = blockIdx.x * 128;

    float best[8], sec[8];
    int   bidx[8];
    #pragma unroll
    for (int s = 0; s < 8; ++s) { best[s] = FLT_MAX; sec[s] = FLT_MAX; bidx[s] = 0; }

    int offA[2], offB[4];
    #pragma unroll
    for (int m = 0; m < 2; ++m) {
        int r = wr * 32 + m * 16 + l15;
        offA[m] = r * 32 + (lhi ^ kswz(r)) * 8;
    }
    #pragma unroll
    for (int n = 0; n < 4; ++n) {
        int r = wc * 64 + n * 16 + l15;
        offB[n] = r * 32 + (lhi ^ kswz(r)) * 8;
    }

    // staging constants: threads 0..511 stage A-hi, 512..1023 stage A-lo;
    // all 1024 stage Bh and Bl (one issue each).
    const int  at   = tid & 511;
    const int  ar   = at >> 2, asl = at & 3;
    const bool aHi  = tid < 512;
    const short* Asrc = aHi ? Ah_g : Al_g;
    const int  adst = (aHi ? 0 : 4096) + at * 8;
    const size_t a_go0 = (size_t)(row0 + ar) * D_DIM + (asl ^ kswz(ar)) * 8;

    const int brr = tid >> 2, bsl = tid & 3;   // 0..255, 0..3
    const int bko = (bsl ^ kswz(brr)) * 8;

    // prologue: stage step 0 into buf 0
    {
        gld16(Asrc + a_go0, smem + adst);
        size_t go = (size_t)brr * D_DIM + bko;
        gld16(Bh_g + go, smem + 8192 + tid * 8);
        gld16(Bl_g + go, smem + 16384 + tid * 8);
    }
    __syncthreads();

    f32x4 acc[2][4];
    #pragma unroll
    for (int m = 0; m < 2; ++m)
        #pragma unroll
        for (int n = 0; n < 4; ++n) acc[m][n] = (f32x4){0.f, 0.f, 0.f, 0.f};

    for (int s = 0; s < 256; ++s) {
        short* cur = smem + (s & 1) * BUFS;

        // issue next step's staging first (latency hides under compute)
        if (s < 255) {
            const int s1 = s + 1;
            const int k0 = (s1 & 15) * 32;
            const int cb0 = (s1 >> 4) * 256;
            short* nb = smem + (s1 & 1) * BUFS;
            gld16(Asrc + a_go0 + k0, nb + adst);
            size_t go = (size_t)(cb0 + brr) * D_DIM + k0 + bko;
            gld16(Bh_g + go, nb + 8192 + tid * 8);
            gld16(Bl_g + go, nb + 16384 + tid * 8);
        }

        s16x8 ah[2], al[2], bh[4], bl[4];
        #pragma unroll
        for (int m = 0; m < 2; ++m) {
            ah[m] = *(const s16x8*)(cur + offA[m]);
            al[m] = *(const s16x8*)(cur + 4096 + offA[m]);
        }
        #pragma unroll
        for (int n = 0; n < 4; ++n) {
            bh[n] = *(const s16x8*)(cur + 8192 + offB[n]);
            bl[n] = *(const s16x8*)(cur + 16384 + offB[n]);
        }

        #pragma unroll
        for (int m = 0; m < 2; ++m)
            #pragma unroll
            for (int n = 0; n < 4; ++n) {
                acc[m][n] = __builtin_amdgcn_mfma_f32_16x16x32_bf16(ah[m], bh[n], acc[m][n], 0, 0, 0);
                acc[m][n] = __builtin_amdgcn_mfma_f32_16x16x32_bf16(ah[m], bl[n], acc[m][n], 0, 0, 0);
                acc[m][n] = __builtin_amdgcn_mfma_f32_16x16x32_bf16(al[m], bh[n], acc[m][n], 0, 0, 0);
            }

        if ((s & 15) == 15) {
            const int cb0 = (s >> 4) * 256;
            #pragma unroll
            for (int n = 0; n < 4; ++n) {
                int c = cb0 + wc * 64 + n * 16 + l15;
                float en = e_norm[c];
                #pragma unroll
                for (int m = 0; m < 2; ++m)
                    #pragma unroll
                    for (int r = 0; r < 4; ++r) {
                        float dv = __fmaf_rn(-2.f, acc[m][n][r], en);
                        int si = m * 4 + r;
                        if (dv < best[si]) { sec[si] = best[si]; best[si] = dv; bidx[si] = c; }
                        else if (dv < sec[si]) sec[si] = dv;
                    }
            }
            #pragma unroll
            for (int m = 0; m < 2; ++m)
                #pragma unroll
                for (int n = 0; n < 4; ++n) acc[m][n] = (f32x4){0.f, 0.f, 0.f, 0.f};
        }

        __syncthreads();
    }

    // intra-wave reduce across the 16 lanes (l15 = columns) sharing each row
    #pragma unroll
    for (int s = 0; s < 8; ++s) {
        float v = best[s], sc = sec[s];
        int ix = bidx[s];
        #pragma unroll
        for (int off = 8; off > 0; off >>= 1) {
            float v2 = __shfl_xor(v, off);
            float s2 = __shfl_xor(sc, off);
            int   i2 = __shfl_xor(ix, off);
            float ns = fminf(fminf(sc, s2), fmaxf(v, v2));
            if (v2 < v || (v2 == v && i2 < ix)) { v = v2; ix = i2; }
            sc = ns;
        }
        best[s] = v; sec[s] = sc; bidx[s] = ix;
    }

    // cross-wave merge via LDS (reuse staging area; last loop barrier passed)
    float* mb = (float*)smem;        // [4][128] (wc-major)
    float* ms = mb + 512;
    int*   mi = (int*)(mb + 1024);
    if (l15 == 0) {
        #pragma unroll
        for (int m = 0; m < 2; ++m)
            #pragma unroll
            for (int r = 0; r < 4; ++r) {
                int s = m * 4 + r;
                int rowblk = wr * 32 + m * 16 + lhi * 4 + r;
                mb[wc * 128 + rowblk] = best[s];
                ms[wc * 128 + rowblk] = sec[s];
                mi[wc * 128 + rowblk] = bidx[s];
            }
    }
    __syncthreads();
    if (tid < 128) {
        float B = FLT_MAX, S = FLT_MAX;
        int I = 0;
        #pragma unroll
        for (int w = 0; w < 4; ++w) {
            float b = mb[w * 128 + tid], s = ms[w * 128 + tid];
            int i = mi[w * 128 + tid];
            if (b < B || (b == B && i < I)) { S = fminf(B, s); B = b; I = i; }
            else S = fminf(S, fminf(b, s));
        }
        int row = row0 + tid;
        fidx[row] = (unsigned short)I;
        if (S - B < EPS_GAP) {
            int p = atomicAdd(flagcnt, 1);
            if (p < FLAG_CAP) flaglist[p] = row;
        }
    }
}

// ---------------------------------------------------------------------------
// Kernel 3: flagged-row resolve — one row per block, 16 waves, x2 unroll.
// (byte-identical to the round-11 version that passed)
// ---------------------------------------------------------------------------
#define FIXT 1024
#define NWAV 16
#define MAXC 128

__global__ __launch_bounds__(FIXT)
void vq_fixrow(const float* __restrict__ lat, const float* __restrict__ emb,
               const int* __restrict__ flagcnt, const int* __restrict__ flaglist,
               unsigned short* __restrict__ fidx)
{
    __shared__ float xs[D_DIM];
    __shared__ float dall[K_CODES];     // 16 KB
    __shared__ float wmin_s[NWAV];
    __shared__ int   ccnt;
    __shared__ int   cands[MAXC];
    __shared__ float cd32[MAXC];

    const int t    = threadIdx.x;
    const int wave = t >> 6;
    const int lane = t & 63;
    int cnt = *flagcnt;
    if (cnt > FLAG_CAP) cnt = FLAG_CAP;

    for (int f = blockIdx.x; f < cnt; f += gridDim.x) {
        const int row = flaglist[f];
        __syncthreads();   // protect LDS reuse across row iterations
        if (t < D_DIM) xs[t] = lat[(size_t)row * D_DIM + t];
        if (t == 0) ccnt = 0;
        __syncthreads();

        float x8[8];
        #pragma unroll
        for (int q = 0; q < 8; ++q) x8[q] = xs[lane * 8 + q];

        float lmin = FLT_MAX;
        for (int c = wave; c < K_CODES; c += 2 * NWAV) {
            const int c2 = c + NWAV;
            const float4* e4a = (const float4*)(emb + (size_t)c  * D_DIM);
            const float4* e4b = (const float4*)(emb + (size_t)c2 * D_DIM);
            float4 ea0 = e4a[lane * 2], ea1 = e4a[lane * 2 + 1];
            float4 eb0 = e4b[lane * 2], eb1 = e4b[lane * 2 + 1];

            float p0 = x8[0] - ea0.x, p1 = x8[1] - ea0.y;
            float p2 = x8[2] - ea0.z, p3 = x8[3] - ea0.w;
            float p4 = x8[4] - ea1.x, p5 = x8[5] - ea1.y;
            float p6 = x8[6] - ea1.z, p7 = x8[7] - ea1.w;
            float sA = __fmaf_rn(p0, p0, __fmaf_rn(p1, p1, __fmaf_rn(p2, p2, p3 * p3)));
            float sB = __fmaf_rn(p4, p4, __fmaf_rn(p5, p5, __fmaf_rn(p6, p6, p7 * p7)));
            float u = sA + sB;

            float q0 = x8[0] - eb0.x, q1 = x8[1] - eb0.y;
            float q2 = x8[2] - eb0.z, q3 = x8[3] - eb0.w;
            float q4 = x8[4] - eb1.x, q5 = x8[5] - eb1.y;
            float q6 = x8[6] - eb1.z, q7 = x8[7] - eb1.w;
            float tA = __fmaf_rn(q0, q0, __fmaf_rn(q1, q1, __fmaf_rn(q2, q2, q3 * q3)));
            float tB = __fmaf_rn(q4, q4, __fmaf_rn(q5, q5, __fmaf_rn(q6, q6, q7 * q7)));
            float v = tA + tB;

            #pragma unroll
            for (int off = 32; off > 0; off >>= 1) {
                u += __shfl_xor(u, off);
                v += __shfl_xor(v, off);
            }
            if (lane == 0) { dall[c] = u; dall[c2] = v; }
            lmin = fminf(lmin, fminf(u, v));
        }
        if (lane == 0) wmin_s[wave] = lmin;
        __syncthreads();

        float gmin = wmin_s[0];
        #pragma unroll
        for (int w = 1; w < NWAV; ++w) gmin = fminf(gmin, wmin_s[w]);
        const float thr = gmin + CAND_WIN;

        for (int c = t; c < K_CODES; c += FIXT) {
            if (dall[c] < thr) {
                int p = atomicAdd(&ccnt, 1);
                if (p < MAXC) cands[p] = c;
            }
        }
        __syncthreads();

        int nc = ccnt < MAXC ? ccnt : MAXC;
        if (t < nc) {
            int c = cands[t];
            const float* e = emb + (size_t)c * D_DIM;
            float t1 = np_sum512_sq(xs);
            float t2 = np_sum512_sq(e);
            float dot = 0.f;
            for (int k = 0; k < D_DIM; ++k)
                dot = __fmaf_rn(xs[k], e[k], dot);     // sequential, BLAS order
            cd32[t] = __fsub_rn(__fadd_rn(t1, t2), __fmul_rn(2.f, dot));
        }
        __syncthreads();

        if (t == 0) {
            float bv = cd32[0]; int bx = cands[0];
            for (int w = 1; w < nc; ++w)
                if (cd32[w] < bv || (cd32[w] == bv && cands[w] < bx)) {
                    bv = cd32[w]; bx = cands[w];
                }
            fidx[row] = (unsigned short)bx;
        }
    }
}

// ---------------------------------------------------------------------------
// Kernel 4: gather quantized rows, per-row MSE partial, histogram.
// ---------------------------------------------------------------------------
__global__ void vq_gather(const float* __restrict__ lat, const float* __restrict__ emb,
                          const unsigned short* __restrict__ fidx,
                          float* __restrict__ out_q,
                          float* __restrict__ rowpart, int* __restrict__ hist) {
    int row  = blockIdx.x * 4 + (threadIdx.x >> 6);
    int lane = threadIdx.x & 63;
    int idx  = fidx[row];

    if (lane == 0) atomicAdd(&hist[idx], 1);

    const float4* e4 = (const float4*)(emb + (size_t)idx * D_DIM);
    const float4* x4 = (const float4*)(lat + (size_t)row * D_DIM);
    float4*       q4 = (float4*)(out_q + (size_t)row * D_DIM);

    float s = 0.f;
    #pragma unroll
    for (int i = 0; i < 2; ++i) {
        float4 e = e4[i * 64 + lane];
        float4 x = x4[i * 64 + lane];
        q4[i * 64 + lane] = e;
        float dx = e.x - x.x, dy = e.y - x.y, dz = e.z - x.z, dw = e.w - x.w;
        s += dx * dx + dy * dy + dz * dz + dw * dw;
    }
    #pragma unroll
    for (int off = 32; off > 0; off >>= 1) s += __shfl_down(s, off);
    if (lane == 0) rowpart[row] = s;
}

// ---------------------------------------------------------------------------
// Kernel 5: final reductions (loss, perplexity).
// ---------------------------------------------------------------------------
__global__ void vq_finalize(const float* __restrict__ rowpart, const int* __restrict__ hist,
                            float* __restrict__ out_loss, float* __restrict__ out_perp) {
    __shared__ float sdata[256];
    int t = threadIdx.x;

    float s = 0.f;
    for (int i = t; i < N_ROWS; i += 256) s += rowpart[i];
    sdata[t] = s;
    __syncthreads();
    for (int st = 128; st > 0; st >>= 1) {
        if (t < st) sdata[t] += sdata[t + st];
        __syncthreads();
    }
    if (t == 0) out_loss[0] = 1.05f * (sdata[0] / ((float)N_ROWS * (float)D_DIM));
    __syncthreads();

    float p = 0.f;
    for (int i = t; i < K_CODES; i += 256) {
        float pr = (float)hist[i] / (float)N_ROWS;
        p += pr * logf(pr + 1e-10f);
    }
    sdata[t] = p;
    __syncthreads();
    for (int st = 128; st > 0; st >>= 1) {
        if (t < st) sdata[t] += sdata[t + st];
        __syncthreads();
    }
    if (t == 0) out_perp[0] = expf(-sdata[0]);
}

// ---------------------------------------------------------------------------
// Kernel 6: fidx u16 -> out_inds float.
// ---------------------------------------------------------------------------
__global__ void vq_inds(const unsigned short* __restrict__ fidx, float* __restrict__ out_inds) {
    int i = blockIdx.x * 1024 + threadIdx.x;
    out_inds[i] = (float)fidx[i];
}

// ---------------------------------------------------------------------------
extern "C" void kernel_launch(void* const* d_in, const int* in_sizes, int n_in,
                              void* d_out, int out_size, void* d_ws, size_t ws_size,
                              hipStream_t stream) {
    const float* lat = (const float*)d_in[0];
    const float* emb = (const float*)d_in[1];
    float* ob = (float*)d_out;

    short* emb_hi = (short*)(ob + 0);
    short* emb_lo = (short*)(ob + 1048576);
    short* lat_hi = (short*)(ob + 2097152);
    short* lat_lo = (short*)(ob + 10485760);
    float* e_norm = ob + 18874368;
    int*   flagcnt  = (int*)(ob + 18878464);
    int*   flaglist = (int*)(ob + 18878465);
    unsigned short* fidx = (unsigned short*)(ob + 18890496);
    int*   hist    = (int*)(ob + 16777220);
    float* rowpart = ob + 16781316;

    float* out_q    = ob;
    float* out_loss = ob + 16777216;
    float* out_inds = ob + 16777217;
    float* out_emb  = ob + 16809985;
    float* out_perp = ob + 18907137;

    // flagcnt lives in the clean tail (never touched by vq_convert) -> zero now.
    hipMemsetAsync(flagcnt, 0, sizeof(int), stream);

    vq_convert<<<dim3(9216), dim3(256), 0, stream>>>(lat, emb, lat_hi, lat_lo, emb_hi, emb_lo);
    vq_enorm<<<dim3(1024), dim3(256), 0, stream>>>(emb, e_norm);

    vq_argmin_mfma<<<dim3(256), dim3(1024), 0, stream>>>(lat_hi, lat_lo, emb_hi, emb_lo,
                                                         e_norm, fidx, flagcnt, flaglist);

    // hist overlaps lat_lo -> zero it only AFTER the argmin consumed lat_lo.
    hipMemsetAsync(hist, 0, K_CODES * sizeof(int), stream);

    vq_fixrow<<<dim3(512), dim3(FIXT), 0, stream>>>(lat, emb, flagcnt, flaglist, fidx);

    vq_gather<<<dim3(N_ROWS / 4), dim3(256), 0, stream>>>(lat, emb, fidx, out_q, rowpart, hist);

    vq_finalize<<<dim3(1), dim3(256), 0, stream>>>(rowpart, hist, out_loss, out_perp);

    vq_inds<<<dim3(32), dim3(1024), 0, stream>>>(fidx, out_inds);

    hipMemcpyAsync(out_emb, emb, (size_t)K_CODES * D_DIM * sizeof(float),
                   hipMemcpyDeviceToDevice, stream);
}